// Round 1
// baseline (563.983 us; speedup 1.0000x reference)
//
#include <hip/hip_runtime.h>
#include <hip/hip_bf16.h>
#include <math.h>

// Problem constants (from reference)
#define T_LEN 256
#define NSYM 64
#define NVAL 32
#define DMOD 64

__device__ __forceinline__ float gelu_exact(float x) {
    // jax.nn.gelu(approximate=False) = 0.5*x*(1+erf(x/sqrt(2)))
    return 0.5f * x * (1.0f + erff(x * 0.70710678118654752440f));
}
__device__ __forceinline__ float sigmoid_f(float x) {
    return 1.0f / (1.0f + expf(-x));
}

// ---------------------------------------------------------------------------
// K1: fully fused per-batch kernel.
// One block (256 threads) per b:
//   A) load per-event ints, build compacted map/step event lists in LDS
//   B) for each list: gather evidence rows -> LDS, 64x64 fp32 tile-GEMM,
//      GELU + dot(W2) + sigmoid, LDS-atomic scatter into LDS memories
//   C) 3-step graph walk entirely in LDS, write graph_state[b][128] to ws
// map_memory/step_memory NEVER touch global memory.
// ---------------------------------------------------------------------------
__global__ __launch_bounds__(256, 2) void k1_fused(
    const float* __restrict__ evidence,
    const int* __restrict__ event_marker,
    const int* __restrict__ source_idx,
    const int* __restrict__ source_valid,
    const int* __restrict__ tsym_idx,
    const int* __restrict__ tsym_valid,
    const int* __restrict__ tval_idx,
    const int* __restrict__ tval_valid,
    const int* __restrict__ query_idx,
    const int* __restrict__ query_valid,
    const float* __restrict__ symbol_emb,   // [64,64]
    const float* __restrict__ value_emb,    // [32,64]
    const float* __restrict__ mg_W1, const float* __restrict__ mg_b1,
    const float* __restrict__ mg_W2, const float* __restrict__ mg_b2,
    const float* __restrict__ sg_W1, const float* __restrict__ sg_b1,
    const float* __restrict__ sg_W2, const float* __restrict__ sg_b2,
    float* __restrict__ state_out)          // [B,128]
{
    __shared__ int   s_src[T_LEN], s_tv[T_LEN], s_ts[T_LEN];
    __shared__ int   list_map[T_LEN], list_step[T_LEN];
    __shared__ int   cnts[2];
    __shared__ float mapM[NSYM * NVAL];     // 8 KB
    __shared__ float stepM[NSYM * NSYM];    // 16 KB
    __shared__ float W1s[64 * 64];          // 16 KB (reused mg -> sg)
    __shared__ float W2s[64], b1s[64];
    __shared__ float b2s;
    __shared__ float X[64 * 65];            // 64 events x 64 feats, pad 65
    __shared__ float wk[64], wk2[64], accv[32], accs[64];

    const int tid = threadIdx.x;
    const int b   = blockIdx.x;

    // ---- phase A: ints, masks, lists, zero memories ----
    if (tid < 2) cnts[tid] = 0;
    for (int i = tid; i < NSYM * NVAL;  i += 256) mapM[i]  = 0.f;
    for (int i = tid; i < NSYM * NSYM;  i += 256) stepM[i] = 0.f;
    __syncthreads();

    {
        const int e  = b * T_LEN + tid;
        const int m  = event_marker[e];
        const int sv = source_valid[e];
        int src = source_idx[e]; src = src < 0 ? 0 : (src > 63 ? 63 : src);
        int ts  = tsym_idx[e];   ts  = ts  < 0 ? 0 : (ts  > 63 ? 63 : ts);
        int tv  = tval_idx[e];   tv  = tv  < 0 ? 0 : (tv  > 31 ? 31 : tv);
        s_src[tid] = src; s_ts[tid] = ts; s_tv[tid] = tv;
        const bool mm = ((m == 1) || (m == 2)) && (sv != 0) && (tval_valid[e] != 0);
        const bool sm = (m == 3) && (sv != 0) && (tsym_valid[e] != 0);
        if (mm) { int i = atomicAdd(&cnts[0], 1); list_map[i]  = tid; }
        if (sm) { int i = atomicAdd(&cnts[1], 1); list_step[i] = tid; }
    }
    __syncthreads();

    // ---- phase B: gate MLPs for each event type ----
    for (int type = 0; type < 2; ++type) {
        const float* W1g = (type == 0) ? mg_W1 : sg_W1;
        const float* W2g = (type == 0) ? mg_W2 : sg_W2;
        const float* b1g = (type == 0) ? mg_b1 : sg_b1;
        const float* b2g = (type == 0) ? mg_b2 : sg_b2;
        const int*   list = (type == 0) ? list_map : list_step;

        for (int i = tid; i < 4096; i += 256) W1s[i] = W1g[i];
        if (tid < 64) { W2s[tid] = W2g[tid]; b1s[tid] = b1g[tid]; }
        if (tid == 0) b2s = b2g[0];
        __syncthreads();

        const int cnt = cnts[type];
        for (int tile0 = 0; tile0 < cnt; tile0 += 64) {
            // gather evidence rows for this tile (zero-fill tail)
            {
                const int r = tid >> 2, f4 = tid & 3;
                const int slot = tile0 + r;
                float* xd = &X[r * 65 + f4 * 16];
                if (slot < cnt) {
                    const int tev = list[slot];
                    const float* xg = evidence + ((size_t)(b * T_LEN + tev)) * 64 + f4 * 16;
                    #pragma unroll
                    for (int i = 0; i < 4; ++i) {
                        const float4 v = *reinterpret_cast<const float4*>(xg + i * 4);
                        xd[i * 4 + 0] = v.x; xd[i * 4 + 1] = v.y;
                        xd[i * 4 + 2] = v.z; xd[i * 4 + 3] = v.w;
                    }
                } else {
                    #pragma unroll
                    for (int i = 0; i < 16; ++i) xd[i] = 0.f;
                }
            }
            __syncthreads();

            // 64x64 GEMM: thread owns 2 events x 8 hidden cols
            float acc0[8], acc1[8];
            #pragma unroll
            for (int i = 0; i < 8; ++i) { acc0[i] = 0.f; acc1[i] = 0.f; }
            const int ep = tid >> 3, jo = tid & 7;
            const int j0 = jo * 8;
            const float* xp0 = &X[(ep * 2) * 65];
            const float* xp1 = &X[(ep * 2 + 1) * 65];
            #pragma unroll 8
            for (int k = 0; k < 64; ++k) {
                const float x0 = xp0[k], x1 = xp1[k];
                const float4 w0 = *reinterpret_cast<const float4*>(&W1s[k * 64 + j0]);
                const float4 w1 = *reinterpret_cast<const float4*>(&W1s[k * 64 + j0 + 4]);
                acc0[0] += x0 * w0.x; acc0[1] += x0 * w0.y;
                acc0[2] += x0 * w0.z; acc0[3] += x0 * w0.w;
                acc0[4] += x0 * w1.x; acc0[5] += x0 * w1.y;
                acc0[6] += x0 * w1.z; acc0[7] += x0 * w1.w;
                acc1[0] += x1 * w0.x; acc1[1] += x1 * w0.y;
                acc1[2] += x1 * w0.z; acc1[3] += x1 * w0.w;
                acc1[4] += x1 * w1.x; acc1[5] += x1 * w1.y;
                acc1[6] += x1 * w1.z; acc1[7] += x1 * w1.w;
            }
            // GELU + second layer partial
            float p0 = 0.f, p1 = 0.f;
            #pragma unroll
            for (int jj = 0; jj < 8; ++jj) {
                const float bb = b1s[j0 + jj], ww = W2s[j0 + jj];
                p0 += gelu_exact(acc0[jj] + bb) * ww;
                p1 += gelu_exact(acc1[jj] + bb) * ww;
            }
            // reduce over the 8 jo-lanes (contiguous lanes, xor 1/2/4)
            p0 += __shfl_xor(p0, 1); p0 += __shfl_xor(p0, 2); p0 += __shfl_xor(p0, 4);
            p1 += __shfl_xor(p1, 1); p1 += __shfl_xor(p1, 2); p1 += __shfl_xor(p1, 4);

            if (jo == 0) {
                const float bb2 = b2s;
                const int slot0 = tile0 + ep * 2;
                if (slot0 < cnt) {
                    const int tev = list[slot0];
                    const float g = sigmoid_f(p0 + bb2);
                    if (type == 0) atomicAdd(&mapM[s_src[tev] * NVAL + s_tv[tev]], g);
                    else           atomicAdd(&stepM[s_src[tev] * NSYM + s_ts[tev]], g);
                }
                const int slot1 = slot0 + 1;
                if (slot1 < cnt) {
                    const int tev = list[slot1];
                    const float g = sigmoid_f(p1 + bb2);
                    if (type == 0) atomicAdd(&mapM[s_src[tev] * NVAL + s_tv[tev]], g);
                    else           atomicAdd(&stepM[s_src[tev] * NSYM + s_ts[tev]], g);
                }
            }
            __syncthreads();
        }
        __syncthreads();
    }

    // ---- phase C: 3-step graph walk (memories live in LDS) ----
    {
        int q = query_idx[b]; q = q < 0 ? 0 : (q > 63 ? 63 : q);
        const float qv = (query_valid[b] != 0) ? 1.0f : 0.0f;
        if (tid < 64) wk[tid]  = (tid == q) ? qv : 0.f;
        if (tid < 32) accv[tid] = qv * mapM[q * NVAL + tid];
        if (tid < 64) accs[tid] = qv * symbol_emb[q * 64 + tid];
        __syncthreads();

        for (int st = 0; st < 3; ++st) {
            if (tid < 64) {
                float s = 0.f;
                #pragma unroll 8
                for (int s0 = 0; s0 < 64; ++s0) s += wk[s0] * stepM[s0 * NSYM + tid];
                wk2[tid] = s;
            }
            __syncthreads();
            if (tid < 64) wk[tid] = wk2[tid];
            __syncthreads();
            if (tid < 32) {
                float s = 0.f;
                #pragma unroll 8
                for (int s0 = 0; s0 < 64; ++s0) s += wk[s0] * mapM[s0 * NVAL + tid];
                accv[tid] += s;
            }
            if (tid < 64) {
                float s = 0.f;
                #pragma unroll 8
                for (int s0 = 0; s0 < 64; ++s0) s += wk[s0] * symbol_emb[s0 * 64 + tid];
                accs[tid] += s;
            }
            __syncthreads();
        }

        if (tid < 64) {
            float s = 0.f;
            #pragma unroll 8
            for (int v = 0; v < 32; ++v) s += accv[v] * value_emb[v * 64 + tid];
            state_out[(size_t)b * 128 + tid]      = accs[tid];
            state_out[(size_t)b * 128 + 64 + tid] = s;
        }
    }
}

// ---------------------------------------------------------------------------
// K2: output heads. 4 b-rows per block; wave w handles b, lane j computes
// hidden unit j for both MLPs; LDS transpose; then per-output dots.
// out layout: logits [B*32] then feedback [B*64] (tuple concat).
// ---------------------------------------------------------------------------
__global__ __launch_bounds__(256) void k2_heads(
    const float* __restrict__ state,        // [B,128]
    const float* __restrict__ sf_W1, const float* __restrict__ sf_b1,
    const float* __restrict__ sf_W2, const float* __restrict__ sf_b2,
    const float* __restrict__ oh_W1, const float* __restrict__ oh_b1,
    const float* __restrict__ oh_W2, const float* __restrict__ oh_b2,
    float* __restrict__ out, int B)
{
    __shared__ float h_oh[4][64];
    __shared__ float h_sf[4][64];
    const int tid = threadIdx.x;
    const int w = tid >> 6, j = tid & 63;
    const int b = blockIdx.x * 4 + w;
    {
        const float* st = state + (size_t)b * 128;
        float a_oh = oh_b1[j], a_sf = sf_b1[j];
        #pragma unroll 8
        for (int k = 0; k < 128; ++k) {
            const float sv = st[k];
            a_oh += sv * oh_W1[k * 64 + j];
            a_sf += sv * sf_W1[k * 64 + j];
        }
        h_oh[w][j] = gelu_exact(a_oh);
        h_sf[w][j] = gelu_exact(a_sf);
    }
    __syncthreads();

    for (int o = tid; o < 4 * 96; o += 256) {
        const int bb = o / 96, oo = o % 96;
        const int gb = blockIdx.x * 4 + bb;
        if (oo < 32) {
            float s = oh_b2[oo];
            #pragma unroll 8
            for (int jj = 0; jj < 64; ++jj) s += h_oh[bb][jj] * oh_W2[jj * 32 + oo];
            out[(size_t)gb * 32 + oo] = s;
        } else {
            const int dd = oo - 32;
            float s = sf_b2[dd];
            #pragma unroll 8
            for (int jj = 0; jj < 64; ++jj) s += h_sf[bb][jj] * sf_W2[jj * 64 + dd];
            out[(size_t)B * 32 + (size_t)gb * 64 + dd] = s;
        }
    }
}

extern "C" void kernel_launch(void* const* d_in, const int* in_sizes, int n_in,
                              void* d_out, int out_size, void* d_ws, size_t ws_size,
                              hipStream_t stream) {
    const float* evidence      = (const float*)d_in[0];
    const int*   event_marker  = (const int*)d_in[1];
    const int*   source_idx    = (const int*)d_in[2];
    const int*   source_valid  = (const int*)d_in[3];
    const int*   tsym_idx      = (const int*)d_in[4];
    const int*   tsym_valid    = (const int*)d_in[5];
    const int*   tval_idx      = (const int*)d_in[6];
    const int*   tval_valid    = (const int*)d_in[7];
    const int*   query_idx     = (const int*)d_in[8];
    const int*   query_valid   = (const int*)d_in[9];
    const float* symbol_emb    = (const float*)d_in[10];
    const float* value_emb     = (const float*)d_in[11];
    const float* mg_W1 = (const float*)d_in[12]; const float* mg_b1 = (const float*)d_in[13];
    const float* mg_W2 = (const float*)d_in[14]; const float* mg_b2 = (const float*)d_in[15];
    const float* sg_W1 = (const float*)d_in[16]; const float* sg_b1 = (const float*)d_in[17];
    const float* sg_W2 = (const float*)d_in[18]; const float* sg_b2 = (const float*)d_in[19];
    const float* sf_W1 = (const float*)d_in[20]; const float* sf_b1 = (const float*)d_in[21];
    const float* sf_W2 = (const float*)d_in[22]; const float* sf_b2 = (const float*)d_in[23];
    const float* oh_W1 = (const float*)d_in[24]; const float* oh_b1 = (const float*)d_in[25];
    const float* oh_W2 = (const float*)d_in[26]; const float* oh_b2 = (const float*)d_in[27];

    const int B = in_sizes[8];          // 4096
    float* state = (float*)d_ws;        // [B,128] scratch

    k1_fused<<<B, 256, 0, stream>>>(
        evidence, event_marker, source_idx, source_valid,
        tsym_idx, tsym_valid, tval_idx, tval_valid,
        query_idx, query_valid, symbol_emb, value_emb,
        mg_W1, mg_b1, mg_W2, mg_b2, sg_W1, sg_b1, sg_W2, sg_b2,
        state);

    k2_heads<<<B / 4, 256, 0, stream>>>(
        state, sf_W1, sf_b1, sf_W2, sf_b2,
        oh_W1, oh_b1, oh_W2, oh_b2,
        (float*)d_out, B);
}

// Round 2
// 556.579 us; speedup vs baseline: 1.0133x; 1.0133x over previous
//
#include <hip/hip_runtime.h>
#include <hip/hip_bf16.h>
#include <math.h>

// Problem constants (from reference)
#define T_LEN 256
#define NSYM 64
#define NVAL 32

__device__ __forceinline__ float gelu_exact(float x) {
    // jax.nn.gelu(approximate=False) = 0.5*x*(1+erf(x/sqrt(2)))
    return 0.5f * x * (1.0f + erff(x * 0.70710678118654752440f));
}
__device__ __forceinline__ float sigmoid_f(float x) {
    return 1.0f / (1.0f + expf(-x));
}

// ---------------------------------------------------------------------------
// K1 v2: fully fused per-batch kernel, wave-per-event gate MLPs.
//   A) masks -> compacted event lists in LDS (uchar), packed idx codes
//   B) per wave: W1 column held in 64 VGPRs (lane j = hidden unit j),
//      evidence row via 16 broadcast float4 global loads (L2-hot),
//      64 FMA + GELU + W2 dot + 64-lane shfl reduce + sigmoid,
//      LDS atomicAdd scatter into mapM/stepM. NO syncs inside phase B.
//   C) 3-step graph walk in LDS, write graph_state[b][128].
// LDS ~27 KB (was 63 KB); no W1/X staging at all.
// ---------------------------------------------------------------------------
__global__ __launch_bounds__(256, 4) void k1_fused(
    const float* __restrict__ evidence,
    const int* __restrict__ event_marker,
    const int* __restrict__ source_idx,
    const int* __restrict__ source_valid,
    const int* __restrict__ tsym_idx,
    const int* __restrict__ tsym_valid,
    const int* __restrict__ tval_idx,
    const int* __restrict__ tval_valid,
    const int* __restrict__ query_idx,
    const int* __restrict__ query_valid,
    const float* __restrict__ symbol_emb,   // [64,64]
    const float* __restrict__ value_emb,    // [32,64]
    const float* __restrict__ mg_W1, const float* __restrict__ mg_b1,
    const float* __restrict__ mg_W2, const float* __restrict__ mg_b2,
    const float* __restrict__ sg_W1, const float* __restrict__ sg_b1,
    const float* __restrict__ sg_W2, const float* __restrict__ sg_b2,
    float* __restrict__ state_out)          // [B,128]
{
    __shared__ int   s_code[T_LEN];          // src | ts<<8 | tv<<16
    __shared__ unsigned char l_map[T_LEN], l_step[T_LEN];
    __shared__ int   cnts[2];
    __shared__ float mapM[NSYM * NVAL];      // 8 KB
    __shared__ float stepM[NSYM * NSYM];     // 16 KB
    __shared__ float wk[64], wk2[64], accv[32], accs[64];

    const int tid  = threadIdx.x;
    const int b    = blockIdx.x;
    const int lane = tid & 63;
    const int wv   = tid >> 6;

    // ---- phase A: masks, lists, zero memories ----
    if (tid < 2) cnts[tid] = 0;
    for (int i = tid; i < NSYM * NVAL;  i += 256) mapM[i]  = 0.f;
    for (int i = tid; i < NSYM * NSYM;  i += 256) stepM[i] = 0.f;
    __syncthreads();

    {
        const int e  = b * T_LEN + tid;
        const int m  = event_marker[e];
        const int sv = source_valid[e];
        int src = source_idx[e]; src = src < 0 ? 0 : (src > 63 ? 63 : src);
        int ts  = tsym_idx[e];   ts  = ts  < 0 ? 0 : (ts  > 63 ? 63 : ts);
        int tv  = tval_idx[e];   tv  = tv  < 0 ? 0 : (tv  > 31 ? 31 : tv);
        s_code[tid] = src | (ts << 8) | (tv << 16);
        const bool mm = ((m == 1) || (m == 2)) && (sv != 0) && (tval_valid[e] != 0);
        const bool sm = (m == 3) && (sv != 0) && (tsym_valid[e] != 0);
        if (mm) { int i = atomicAdd(&cnts[0], 1); l_map[i]  = (unsigned char)tid; }
        if (sm) { int i = atomicAdd(&cnts[1], 1); l_step[i] = (unsigned char)tid; }
    }
    __syncthreads();

    // ---- phase B: wave-per-event gate MLPs, weights in registers ----
#define FMA4(v, kb) \
    h0 = fmaf((v).x, w1c[(kb)+0], h0); h1 = fmaf((v).y, w1c[(kb)+1], h1); \
    h2 = fmaf((v).z, w1c[(kb)+2], h2); h3 = fmaf((v).w, w1c[(kb)+3], h3);

    #pragma unroll 1
    for (int type = 0; type < 2; ++type) {
        const int cnt = cnts[type];
        if (cnt == 0) continue;
        const float* __restrict__ W1g = (type == 0) ? mg_W1 : sg_W1;
        const float* __restrict__ W2g = (type == 0) ? mg_W2 : sg_W2;
        const float* __restrict__ b1g = (type == 0) ? mg_b1 : sg_b1;
        const float* __restrict__ b2g = (type == 0) ? mg_b2 : sg_b2;
        const unsigned char* list = (type == 0) ? l_map : l_step;

        // lane j's W1 column (64 VGPRs) — L2-hot after the first blocks
        float w1c[64];
        #pragma unroll
        for (int k = 0; k < 64; ++k) w1c[k] = W1g[k * 64 + lane];
        const float b1j = b1g[lane];
        const float w2j = W2g[lane];
        const float b2v = b2g[0];

        for (int i = wv; i < cnt; i += 4) {
            const int t = list[i];                       // LDS broadcast
            const float4* __restrict__ xr =
                (const float4*)(evidence + ((size_t)b * T_LEN + t) * 64);
            // 8 outstanding broadcast loads to hide L2 latency
            float4 a0 = xr[0], a1 = xr[1], a2 = xr[2],  a3 = xr[3];
            float4 c0 = xr[4], c1 = xr[5], c2 = xr[6],  c3 = xr[7];
            float h0 = b1j, h1 = 0.f, h2 = 0.f, h3 = 0.f;
            FMA4(a0, 0)  FMA4(a1, 4)  FMA4(a2, 8)  FMA4(a3, 12)
            a0 = xr[8]; a1 = xr[9]; a2 = xr[10]; a3 = xr[11];
            FMA4(c0, 16) FMA4(c1, 20) FMA4(c2, 24) FMA4(c3, 28)
            c0 = xr[12]; c1 = xr[13]; c2 = xr[14]; c3 = xr[15];
            FMA4(a0, 32) FMA4(a1, 36) FMA4(a2, 40) FMA4(a3, 44)
            FMA4(c0, 48) FMA4(c1, 52) FMA4(c2, 56) FMA4(c3, 60)

            const float hj = (h0 + h1) + (h2 + h3);
            float gj = gelu_exact(hj) * w2j;
            gj += __shfl_xor(gj, 1);  gj += __shfl_xor(gj, 2);
            gj += __shfl_xor(gj, 4);  gj += __shfl_xor(gj, 8);
            gj += __shfl_xor(gj, 16); gj += __shfl_xor(gj, 32);

            if (lane == 0) {
                const float g = sigmoid_f(gj + b2v);
                const int code = s_code[t];
                if (type == 0)
                    atomicAdd(&mapM[(code & 63) * NVAL + ((code >> 16) & 31)], g);
                else
                    atomicAdd(&stepM[(code & 63) * NSYM + ((code >> 8) & 63)], g);
            }
        }
    }
#undef FMA4
    __syncthreads();

    // ---- phase C: 3-step graph walk (memories live in LDS) ----
    {
        int q = query_idx[b]; q = q < 0 ? 0 : (q > 63 ? 63 : q);
        const float qv = (query_valid[b] != 0) ? 1.0f : 0.0f;
        if (tid < 64) wk[tid]  = (tid == q) ? qv : 0.f;
        if (tid < 32) accv[tid] = qv * mapM[q * NVAL + tid];
        if (tid < 64) accs[tid] = qv * symbol_emb[q * 64 + tid];
        __syncthreads();

        for (int st = 0; st < 3; ++st) {
            if (tid < 64) {
                float s = 0.f;
                #pragma unroll 8
                for (int s0 = 0; s0 < 64; ++s0) s += wk[s0] * stepM[s0 * NSYM + tid];
                wk2[tid] = s;
            }
            __syncthreads();
            if (tid < 64) wk[tid] = wk2[tid];
            __syncthreads();
            if (tid < 32) {
                float s = 0.f;
                #pragma unroll 8
                for (int s0 = 0; s0 < 64; ++s0) s += wk[s0] * mapM[s0 * NVAL + tid];
                accv[tid] += s;
            }
            if (tid < 64) {
                float s = 0.f;
                #pragma unroll 8
                for (int s0 = 0; s0 < 64; ++s0) s += wk[s0] * symbol_emb[s0 * 64 + tid];
                accs[tid] += s;
            }
            __syncthreads();
        }

        if (tid < 64) {
            float s = 0.f;
            #pragma unroll 8
            for (int v = 0; v < 32; ++v) s += accv[v] * value_emb[v * 64 + tid];
            state_out[(size_t)b * 128 + tid]      = accs[tid];
            state_out[(size_t)b * 128 + 64 + tid] = s;
        }
    }
}

// ---------------------------------------------------------------------------
// K2: output heads (unchanged from R1 — isolating the k1 change).
// out layout: logits [B*32] then feedback [B*64] (tuple concat).
// ---------------------------------------------------------------------------
__global__ __launch_bounds__(256) void k2_heads(
    const float* __restrict__ state,        // [B,128]
    const float* __restrict__ sf_W1, const float* __restrict__ sf_b1,
    const float* __restrict__ sf_W2, const float* __restrict__ sf_b2,
    const float* __restrict__ oh_W1, const float* __restrict__ oh_b1,
    const float* __restrict__ oh_W2, const float* __restrict__ oh_b2,
    float* __restrict__ out, int B)
{
    __shared__ float h_oh[4][64];
    __shared__ float h_sf[4][64];
    const int tid = threadIdx.x;
    const int w = tid >> 6, j = tid & 63;
    const int b = blockIdx.x * 4 + w;
    {
        const float* st = state + (size_t)b * 128;
        float a_oh = oh_b1[j], a_sf = sf_b1[j];
        #pragma unroll 8
        for (int k = 0; k < 128; ++k) {
            const float sv = st[k];
            a_oh += sv * oh_W1[k * 64 + j];
            a_sf += sv * sf_W1[k * 64 + j];
        }
        h_oh[w][j] = gelu_exact(a_oh);
        h_sf[w][j] = gelu_exact(a_sf);
    }
    __syncthreads();

    for (int o = tid; o < 4 * 96; o += 256) {
        const int bb = o / 96, oo = o % 96;
        const int gb = blockIdx.x * 4 + bb;
        if (oo < 32) {
            float s = oh_b2[oo];
            #pragma unroll 8
            for (int jj = 0; jj < 64; ++jj) s += h_oh[bb][jj] * oh_W2[jj * 32 + oo];
            out[(size_t)gb * 32 + oo] = s;
        } else {
            const int dd = oo - 32;
            float s = sf_b2[dd];
            #pragma unroll 8
            for (int jj = 0; jj < 64; ++jj) s += h_sf[bb][jj] * sf_W2[jj * 64 + dd];
            out[(size_t)B * 32 + (size_t)gb * 64 + dd] = s;
        }
    }
}

extern "C" void kernel_launch(void* const* d_in, const int* in_sizes, int n_in,
                              void* d_out, int out_size, void* d_ws, size_t ws_size,
                              hipStream_t stream) {
    const float* evidence      = (const float*)d_in[0];
    const int*   event_marker  = (const int*)d_in[1];
    const int*   source_idx    = (const int*)d_in[2];
    const int*   source_valid  = (const int*)d_in[3];
    const int*   tsym_idx      = (const int*)d_in[4];
    const int*   tsym_valid    = (const int*)d_in[5];
    const int*   tval_idx      = (const int*)d_in[6];
    const int*   tval_valid    = (const int*)d_in[7];
    const int*   query_idx     = (const int*)d_in[8];
    const int*   query_valid   = (const int*)d_in[9];
    const float* symbol_emb    = (const float*)d_in[10];
    const float* value_emb     = (const float*)d_in[11];
    const float* mg_W1 = (const float*)d_in[12]; const float* mg_b1 = (const float*)d_in[13];
    const float* mg_W2 = (const float*)d_in[14]; const float* mg_b2 = (const float*)d_in[15];
    const float* sg_W1 = (const float*)d_in[16]; const float* sg_b1 = (const float*)d_in[17];
    const float* sg_W2 = (const float*)d_in[18]; const float* sg_b2 = (const float*)d_in[19];
    const float* sf_W1 = (const float*)d_in[20]; const float* sf_b1 = (const float*)d_in[21];
    const float* sf_W2 = (const float*)d_in[22]; const float* sf_b2 = (const float*)d_in[23];
    const float* oh_W1 = (const float*)d_in[24]; const float* oh_b1 = (const float*)d_in[25];
    const float* oh_W2 = (const float*)d_in[26]; const float* oh_b2 = (const float*)d_in[27];

    const int B = in_sizes[8];          // 4096
    float* state = (float*)d_ws;        // [B,128] scratch

    k1_fused<<<B, 256, 0, stream>>>(
        evidence, event_marker, source_idx, source_valid,
        tsym_idx, tsym_valid, tval_idx, tval_valid,
        query_idx, query_valid, symbol_emb, value_emb,
        mg_W1, mg_b1, mg_W2, mg_b2, sg_W1, sg_b1, sg_W2, sg_b2,
        state);

    k2_heads<<<B / 4, 256, 0, stream>>>(
        state, sf_W1, sf_b1, sf_W2, sf_b2,
        oh_W1, oh_b1, oh_W2, oh_b2,
        (float*)d_out, B);
}

// Round 5
// 508.907 us; speedup vs baseline: 1.1082x; 1.0937x over previous
//
#include <hip/hip_runtime.h>
#include <hip/hip_bf16.h>
#include <math.h>

// Problem constants (from reference)
#define T_LEN 256
#define NSYM 64
#define NVAL 32

__device__ __forceinline__ float gelu_exact(float x) {
    // jax.nn.gelu(approximate=False) = 0.5*x*(1+erf(x/sqrt(2)))
    return 0.5f * x * (1.0f + erff(x * 0.70710678118654752440f));
}
__device__ __forceinline__ float sigmoid_f(float x) {
    return 1.0f / (1.0f + expf(-x));
}

// ---------------------------------------------------------------------------
// K1 v3: fully fused per-batch kernel, wave-per-event gate MLPs.
// Fix vs v2: (a) launch_bounds(256,2) so the 64-reg W1 column is NOT spilled
// to scratch (v2's VGPR_Count=64 proved the spill); (b) the event's evidence
// row is loaded through the SCALAR path (readfirstlane -> uniform pointer ->
// s_load), so row values live in SGPRs and vector register pressure drops.
//   A) masks -> compacted event lists in LDS (uchar), packed idx codes
//   B) per wave: W1 column in 64 VGPRs (lane j = hidden unit j), evidence row
//      in SGPRs, 64 FMA + GELU + W2 dot + 64-lane shfl reduce + sigmoid,
//      LDS atomicAdd scatter into mapM/stepM. NO syncs inside phase B.
//   C) 3-step graph walk in LDS, write graph_state[b][128].
// ---------------------------------------------------------------------------
__global__ __launch_bounds__(256, 2) void k1_fused(
    const float* __restrict__ evidence,
    const int* __restrict__ event_marker,
    const int* __restrict__ source_idx,
    const int* __restrict__ source_valid,
    const int* __restrict__ tsym_idx,
    const int* __restrict__ tsym_valid,
    const int* __restrict__ tval_idx,
    const int* __restrict__ tval_valid,
    const int* __restrict__ query_idx,
    const int* __restrict__ query_valid,
    const float* __restrict__ symbol_emb,   // [64,64]
    const float* __restrict__ value_emb,    // [32,64]
    const float* __restrict__ mg_W1, const float* __restrict__ mg_b1,
    const float* __restrict__ mg_W2, const float* __restrict__ mg_b2,
    const float* __restrict__ sg_W1, const float* __restrict__ sg_b1,
    const float* __restrict__ sg_W2, const float* __restrict__ sg_b2,
    float* __restrict__ state_out)          // [B,128]
{
    __shared__ int   s_code[T_LEN];          // src | ts<<8 | tv<<16
    __shared__ unsigned char l_map[T_LEN], l_step[T_LEN];
    __shared__ int   cnts[2];
    __shared__ float mapM[NSYM * NVAL];      // 8 KB
    __shared__ float stepM[NSYM * NSYM];     // 16 KB
    __shared__ float wk[64], wk2[64], accv[32], accs[64];

    const int tid  = threadIdx.x;
    const int b    = blockIdx.x;
    const int lane = tid & 63;
    const int wv   = tid >> 6;

    // ---- phase A: masks, lists, zero memories ----
    if (tid < 2) cnts[tid] = 0;
    for (int i = tid; i < NSYM * NVAL;  i += 256) mapM[i]  = 0.f;
    for (int i = tid; i < NSYM * NSYM;  i += 256) stepM[i] = 0.f;
    __syncthreads();

    {
        const int e  = b * T_LEN + tid;
        const int m  = event_marker[e];
        const int sv = source_valid[e];
        int src = source_idx[e]; src = src < 0 ? 0 : (src > 63 ? 63 : src);
        int ts  = tsym_idx[e];   ts  = ts  < 0 ? 0 : (ts  > 63 ? 63 : ts);
        int tv  = tval_idx[e];   tv  = tv  < 0 ? 0 : (tv  > 31 ? 31 : tv);
        s_code[tid] = src | (ts << 8) | (tv << 16);
        const bool mm = ((m == 1) || (m == 2)) && (sv != 0) && (tval_valid[e] != 0);
        const bool sm = (m == 3) && (sv != 0) && (tsym_valid[e] != 0);
        if (mm) { int i = atomicAdd(&cnts[0], 1); l_map[i]  = (unsigned char)tid; }
        if (sm) { int i = atomicAdd(&cnts[1], 1); l_step[i] = (unsigned char)tid; }
    }
    __syncthreads();

    // ---- phase B: wave-per-event gate MLPs, weights in registers ----
#define FMA4(v, kb) \
    h0 = fmaf((v).x, w1c[(kb)+0], h0); h1 = fmaf((v).y, w1c[(kb)+1], h1); \
    h2 = fmaf((v).z, w1c[(kb)+2], h2); h3 = fmaf((v).w, w1c[(kb)+3], h3);

    #pragma unroll 1
    for (int type = 0; type < 2; ++type) {
        const int cnt = cnts[type];
        if (cnt == 0) continue;
        const float* __restrict__ W1g = (type == 0) ? mg_W1 : sg_W1;
        const float* __restrict__ W2g = (type == 0) ? mg_W2 : sg_W2;
        const float* __restrict__ b1g = (type == 0) ? mg_b1 : sg_b1;
        const float* __restrict__ b2g = (type == 0) ? mg_b2 : sg_b2;
        const unsigned char* list = (type == 0) ? l_map : l_step;

        // lane j's W1 column (64 VGPRs) — L2-hot after the first blocks
        float w1c[64];
        #pragma unroll
        for (int k = 0; k < 64; ++k) w1c[k] = W1g[k * 64 + lane];
        const float b1j = b1g[lane];
        const float w2j = W2g[lane];
        const float b2v = b2g[0];

        #pragma unroll 1
        for (int i = wv; i < cnt; i += 4) {
            // t is identical across the wave (same LDS slot) -> make it SGPR
            // so the evidence row goes through the scalar/SMEM path.
            const int t = __builtin_amdgcn_readfirstlane((int)list[i]);
            const float4* __restrict__ xr =
                (const float4*)(evidence + ((size_t)b * T_LEN + t) * 64);
            const float4 a0 = xr[0],  a1 = xr[1],  a2 = xr[2],  a3 = xr[3];
            const float4 a4 = xr[4],  a5 = xr[5],  a6 = xr[6],  a7 = xr[7];
            const float4 a8 = xr[8],  a9 = xr[9],  aA = xr[10], aB = xr[11];
            const float4 aC = xr[12], aD = xr[13], aE = xr[14], aF = xr[15];
            float h0 = b1j, h1 = 0.f, h2 = 0.f, h3 = 0.f;
            FMA4(a0, 0)   FMA4(a1, 4)   FMA4(a2, 8)   FMA4(a3, 12)
            FMA4(a4, 16)  FMA4(a5, 20)  FMA4(a6, 24)  FMA4(a7, 28)
            FMA4(a8, 32)  FMA4(a9, 36)  FMA4(aA, 40)  FMA4(aB, 44)
            FMA4(aC, 48)  FMA4(aD, 52)  FMA4(aE, 56)  FMA4(aF, 60)

            const float hj = (h0 + h1) + (h2 + h3);
            float gj = gelu_exact(hj) * w2j;
            gj += __shfl_xor(gj, 1);  gj += __shfl_xor(gj, 2);
            gj += __shfl_xor(gj, 4);  gj += __shfl_xor(gj, 8);
            gj += __shfl_xor(gj, 16); gj += __shfl_xor(gj, 32);

            if (lane == 0) {
                const float g = sigmoid_f(gj + b2v);
                const int code = s_code[t];
                if (type == 0)
                    atomicAdd(&mapM[(code & 63) * NVAL + ((code >> 16) & 31)], g);
                else
                    atomicAdd(&stepM[(code & 63) * NSYM + ((code >> 8) & 63)], g);
            }
        }
    }
#undef FMA4
    __syncthreads();

    // ---- phase C: 3-step graph walk (memories live in LDS) ----
    {
        int q = query_idx[b]; q = q < 0 ? 0 : (q > 63 ? 63 : q);
        const float qv = (query_valid[b] != 0) ? 1.0f : 0.0f;
        if (tid < 64) wk[tid]  = (tid == q) ? qv : 0.f;
        if (tid < 32) accv[tid] = qv * mapM[q * NVAL + tid];
        if (tid < 64) accs[tid] = qv * symbol_emb[q * 64 + tid];
        __syncthreads();

        for (int st = 0; st < 3; ++st) {
            if (tid < 64) {
                float s = 0.f;
                #pragma unroll 8
                for (int s0 = 0; s0 < 64; ++s0) s += wk[s0] * stepM[s0 * NSYM + tid];
                wk2[tid] = s;
            }
            __syncthreads();
            if (tid < 64) wk[tid] = wk2[tid];
            __syncthreads();
            if (tid < 32) {
                float s = 0.f;
                #pragma unroll 8
                for (int s0 = 0; s0 < 64; ++s0) s += wk[s0] * mapM[s0 * NVAL + tid];
                accv[tid] += s;
            }
            if (tid < 64) {
                float s = 0.f;
                #pragma unroll 8
                for (int s0 = 0; s0 < 64; ++s0) s += wk[s0] * symbol_emb[s0 * 64 + tid];
                accs[tid] += s;
            }
            __syncthreads();
        }

        if (tid < 64) {
            float s = 0.f;
            #pragma unroll 8
            for (int v = 0; v < 32; ++v) s += accv[v] * value_emb[v * 64 + tid];
            state_out[(size_t)b * 128 + tid]      = accs[tid];
            state_out[(size_t)b * 128 + 64 + tid] = s;
        }
    }
}

// ---------------------------------------------------------------------------
// K2: output heads (unchanged — isolating the k1 change).
// out layout: logits [B*32] then feedback [B*64] (tuple concat).
// ---------------------------------------------------------------------------
__global__ __launch_bounds__(256) void k2_heads(
    const float* __restrict__ state,        // [B,128]
    const float* __restrict__ sf_W1, const float* __restrict__ sf_b1,
    const float* __restrict__ sf_W2, const float* __restrict__ sf_b2,
    const float* __restrict__ oh_W1, const float* __restrict__ oh_b1,
    const float* __restrict__ oh_W2, const float* __restrict__ oh_b2,
    float* __restrict__ out, int B)
{
    __shared__ float h_oh[4][64];
    __shared__ float h_sf[4][64];
    const int tid = threadIdx.x;
    const int w = tid >> 6, j = tid & 63;
    const int b = blockIdx.x * 4 + w;
    {
        const float* st = state + (size_t)b * 128;
        float a_oh = oh_b1[j], a_sf = sf_b1[j];
        #pragma unroll 8
        for (int k = 0; k < 128; ++k) {
            const float sv = st[k];
            a_oh += sv * oh_W1[k * 64 + j];
            a_sf += sv * sf_W1[k * 64 + j];
        }
        h_oh[w][j] = gelu_exact(a_oh);
        h_sf[w][j] = gelu_exact(a_sf);
    }
    __syncthreads();

    for (int o = tid; o < 4 * 96; o += 256) {
        const int bb = o / 96, oo = o % 96;
        const int gb = blockIdx.x * 4 + bb;
        if (oo < 32) {
            float s = oh_b2[oo];
            #pragma unroll 8
            for (int jj = 0; jj < 64; ++jj) s += h_oh[bb][jj] * oh_W2[jj * 32 + oo];
            out[(size_t)gb * 32 + oo] = s;
        } else {
            const int dd = oo - 32;
            float s = sf_b2[dd];
            #pragma unroll 8
            for (int jj = 0; jj < 64; ++jj) s += h_sf[bb][jj] * sf_W2[jj * 64 + dd];
            out[(size_t)B * 32 + (size_t)gb * 64 + dd] = s;
        }
    }
}

extern "C" void kernel_launch(void* const* d_in, const int* in_sizes, int n_in,
                              void* d_out, int out_size, void* d_ws, size_t ws_size,
                              hipStream_t stream) {
    const float* evidence      = (const float*)d_in[0];
    const int*   event_marker  = (const int*)d_in[1];
    const int*   source_idx    = (const int*)d_in[2];
    const int*   source_valid  = (const int*)d_in[3];
    const int*   tsym_idx      = (const int*)d_in[4];
    const int*   tsym_valid    = (const int*)d_in[5];
    const int*   tval_idx      = (const int*)d_in[6];
    const int*   tval_valid    = (const int*)d_in[7];
    const int*   query_idx     = (const int*)d_in[8];
    const int*   query_valid   = (const int*)d_in[9];
    const float* symbol_emb    = (const float*)d_in[10];
    const float* value_emb     = (const float*)d_in[11];
    const float* mg_W1 = (const float*)d_in[12]; const float* mg_b1 = (const float*)d_in[13];
    const float* mg_W2 = (const float*)d_in[14]; const float* mg_b2 = (const float*)d_in[15];
    const float* sg_W1 = (const float*)d_in[16]; const float* sg_b1 = (const float*)d_in[17];
    const float* sg_W2 = (const float*)d_in[18]; const float* sg_b2 = (const float*)d_in[19];
    const float* sf_W1 = (const float*)d_in[20]; const float* sf_b1 = (const float*)d_in[21];
    const float* sf_W2 = (const float*)d_in[22]; const float* sf_b2 = (const float*)d_in[23];
    const float* oh_W1 = (const float*)d_in[24]; const float* oh_b1 = (const float*)d_in[25];
    const float* oh_W2 = (const float*)d_in[26]; const float* oh_b2 = (const float*)d_in[27];

    const int B = in_sizes[8];          // 4096
    float* state = (float*)d_ws;        // [B,128] scratch

    k1_fused<<<B, 256, 0, stream>>>(
        evidence, event_marker, source_idx, source_valid,
        tsym_idx, tsym_valid, tval_idx, tval_valid,
        query_idx, query_valid, symbol_emb, value_emb,
        mg_W1, mg_b1, mg_W2, mg_b2, sg_W1, sg_b1, sg_W2, sg_b2,
        state);

    k2_heads<<<B / 4, 256, 0, stream>>>(
        state, sf_W1, sf_b1, sf_W2, sf_b2,
        oh_W1, oh_b1, oh_W2, oh_b2,
        (float*)d_out, B);
}